// Round 3
// baseline (269.977 us; speedup 1.0000x reference)
//
#include <hip/hip_runtime.h>

// PolylineEncoder: h = relu(X@W1+b1); feat = h@W2+b2; masked max over N=64 points.
// B=32 P=512 N=64 C=9 H=128.
// R10: wave-per-polyline, fully register-resident layer1->layer2 handoff.
//   - Each wave computes ALL 128 h for its own polyline, packs to bf16, and
//     transposes h->k fragments IN REGISTERS via v_permlane32/16_swap_b32
//     (2 swaps per packed word).  No Hb LDS, NO barriers at all.
//   - Polyline processed in two 32-point halves to cap register pressure
//     (Pp[8][2][2] = 32 VGPRs live instead of 64).
//   - LDS = per-wave X staging only (4 x 2304B), per-wave s_waitcnt vmcnt(0).
//   - Same MFMA count per polyline as R9; prep1 weight layouts unchanged.
// R9 lesson: barrier-count surgery alone was neutral -> the cost is the
// non-MFMA instruction stream + cross-wave exchange; this removes both.

using bf16x8 = __attribute__((ext_vector_type(8))) short;
using f32x4  = __attribute__((ext_vector_type(4))) float;

#define MFMA32(A,B,C) __builtin_amdgcn_mfma_f32_16x16x32_bf16((A),(B),(C),0,0,0)

__device__ __forceinline__ f32x4 vmax4(f32x4 a, f32x4 b) {
  return __builtin_elementwise_max(a, b);
}

__device__ __forceinline__ unsigned short f2bf(float f) {
  union { float f; unsigned int u; } v; v.f = f;
  unsigned int r = v.u + 0x7fffu + ((v.u >> 16) & 1u);  // RNE
  return (unsigned short)(r >> 16);
}

// hardware packed f32->bf16 (RNE), low=a high=b: 1 VALU per 2 elems
__device__ __forceinline__ unsigned int pk2(float a, float b) {
  unsigned int r;
  asm("v_cvt_pk_bf16_f32 %0, %1, %2" : "=v"(r) : "v"(a), "v"(b));
  return r;
}

__device__ __forceinline__ f32x4 shfl_xor4(f32x4 v, int m) {
  f32x4 r;
  r[0] = __shfl_xor(v[0], m);
  r[1] = __shfl_xor(v[1], m);
  r[2] = __shfl_xor(v[2], m);
  r[3] = __shfl_xor(v[3], m);
  return r;
}

// ---------------- prep1: mask sniff + frag-swizzled weights ----------------
// ws: w1sw @0 (8KB) | w2sw @8192 (32KB) | flag @40960
__global__ void prep1(const float* __restrict__ W1, const float* __restrict__ W2,
                      const void* __restrict__ mask,
                      unsigned short* __restrict__ w1sw, unsigned short* __restrict__ w2sw,
                      int* __restrict__ flag) {
  int b = blockIdx.x, t = threadIdx.x;
  if (b == 0) {                      // mask storage sniff over 4096 bytes
    __shared__ int cnt;
    if (t == 0) cnt = 0;
    __syncthreads();
    const unsigned char* mb = (const unsigned char*)mask;
    int local = 0;
    for (int i = t * 16; i < t * 16 + 16; i++) local += (mb[i] != 0) ? 1 : 0;
    atomicAdd(&cnt, local);
    __syncthreads();
    if (t == 0) *flag = (cnt > 2800) ? 1 : 0;   // 1 = byte-wise mask, else int32-wise
  } else if (b <= 2) {
    // w1 A-frags (16x16x32): entry e = th*64 + lane; h=(e>>6)*16+(lane&15)
    int e = (b - 1) * 256 + t;       // 512 entries x 8 halves = 8KB
    int lane = e & 63, grp = e >> 6;
    int li = lane & 15, q = lane >> 4;
    int h = grp * 16 + li;
    int c0 = q * 8;
    #pragma unroll
    for (int j = 0; j < 8; j++) {
      int c = c0 + j;
      w1sw[e * 8 + j] = f2bf((c < 9) ? W1[c * 128 + h] : 0.f);
    }
  } else {
    // w2 A-frags (16x16x32): entry e = (wr*16+ks*4+td)*64 + lane; 8 halves each
    int e = (b - 3) * 256 + t;       // 2048 entries x 8 halves = 32KB
    if (e < 2048) {
      int lane = e & 63, grp = e >> 6;
      int wr = grp >> 4, sub = grp & 15;
      int ks = sub >> 2, td = sub & 3;
      int li = lane & 15, q = lane >> 4;
      int d = wr * 64 + td * 16 + li;
      int h0 = ks * 32 + q * 8;
      #pragma unroll
      for (int j = 0; j < 8; j++)
        w2sw[e * 8 + j] = f2bf(W2[(h0 + j) * 128 + d]);
    }
  }
}

// ---------------- main ----------------
// 4 waves/block, one polyline per wave.  LDS: 4 x 2304B X staging regions.
// No __syncthreads anywhere.
__global__ __launch_bounds__(256, 4) void poly_main_k(
    const float* __restrict__ X, const void* __restrict__ mask,
    const float* __restrict__ b1g, const float* __restrict__ b2g,
    const unsigned short* __restrict__ w1sw, const unsigned short* __restrict__ w2sw,
    const int* __restrict__ flagp, float* __restrict__ out)
{
  __shared__ __align__(16) unsigned char smem[9216];

  const int tid  = threadIdx.x;
  const int lane = tid & 63;
  const int w    = tid >> 6;
  const int li   = lane & 15, q = lane >> 4;
  const long long poly = (long long)blockIdx.x * 4 + w;

  // ---- stage own polyline's X (2304B) into own LDS region ----
  {
    const char* xg = (const char*)X + poly * 2304;
    char* xl = (char*)smem + w * 2304;
    __builtin_amdgcn_global_load_lds(
        (const __attribute__((address_space(1))) unsigned int*)(xg + lane * 16),
        (__attribute__((address_space(3))) unsigned int*)xl, 16, 0, 0);
    __builtin_amdgcn_global_load_lds(
        (const __attribute__((address_space(1))) unsigned int*)(xg + 1024 + lane * 16),
        (__attribute__((address_space(3))) unsigned int*)(xl + 1024), 16, 0, 0);
    if (lane < 16)
      __builtin_amdgcn_global_load_lds(
          (const __attribute__((address_space(1))) unsigned int*)(xg + 2048 + lane * 16),
          (__attribute__((address_space(3))) unsigned int*)(xl + 2048), 16, 0, 0);
  }

  // ---- mask: 4 direct loads per lane (64B line in byte case) ----
  float mf[4];
  {
    int flag = *flagp;
    long long mb = poly * 64 + li;
    if (flag) {
      const unsigned char* mp = (const unsigned char*)mask;
      #pragma unroll
      for (int tm = 0; tm < 4; tm++) mf[tm] = mp[mb + tm * 16] ? 0.f : -4e9f;
    } else {
      const int* mp = (const int*)mask;
      #pragma unroll
      for (int tm = 0; tm < 4; tm++) mf[tm] = mp[mb + tm * 16] ? 0.f : -4e9f;
    }
  }

  asm volatile("s_waitcnt vmcnt(0)" ::: "memory");  // own staging complete

  const float* Xw = (const float*)(smem + w * 2304);

  f32x4 pooled[8];
  #pragma unroll
  for (int hf = 0; hf < 2; hf++) {
    // ---- layer-1 B-frags for this half's 2 m-tiles ----
    bf16x8 bx2[2];
    #pragma unroll
    for (int t = 0; t < 2; t++) {
      const float* xr = Xw + ((hf * 2 + t) * 16 + li) * 9;
      union { bf16x8 v; unsigned int u[4]; } uu;
      uu.u[0] = uu.u[1] = uu.u[2] = uu.u[3] = 0u;
      if (q == 0) {
        uu.u[0] = pk2(xr[0], xr[1]); uu.u[1] = pk2(xr[2], xr[3]);
        uu.u[2] = pk2(xr[4], xr[5]); uu.u[3] = pk2(xr[6], xr[7]);
      } else if (q == 1) {
        uu.u[0] = pk2(xr[8], 0.f);
      }
      bx2[t] = uu.v;
    }

    // ---- layer 1: all 128 h for this half's 32 points -> packed bf16 ----
    // Pp[th][t][p]: packed (h = th*16 + q*4 + {2p, 2p+1}) for m-tile t
    unsigned int Pp[8][2][2];
    #pragma unroll
    for (int th = 0; th < 8; th++) {
      bf16x8 a1 = *(const bf16x8*)(w1sw + (th * 64 + lane) * 8);
      f32x4 bv = *(const f32x4*)(b1g + th * 16 + q * 4);
      f32x4 acc[2];
      acc[0] = bv; acc[1] = bv;
      acc[0] = MFMA32(a1, bx2[0], acc[0]);
      acc[1] = MFMA32(a1, bx2[1], acc[1]);
      #pragma unroll
      for (int t = 0; t < 2; t++) {
        f32x4 v = vmax4(acc[t], f32x4{0.f, 0.f, 0.f, 0.f});
        Pp[th][t][0] = pk2(v[0], v[1]);
        Pp[th][t][1] = pk2(v[2], v[3]);
      }
    }

    // ---- per m-tile: in-register h->k transpose + layer 2 + pool ----
    #pragma unroll
    for (int t = 0; t < 2; t++) {
      const int tm = hf * 2 + t;
      f32x4 acc2[8];
      #pragma unroll
      for (int td = 0; td < 8; td++) acc2[td] = f32x4{0.f, 0.f, 0.f, 0.f};
      #pragma unroll
      for (int ks = 0; ks < 4; ks++) {
        // 4x4 lane-quadrant transpose, in place, 2 swaps per packed word:
        // after swaps: Pp[2ks][t][p] = [X.q0,X.q2,Y.q0,Y.q2] (B-word p)
        //              Pp[2ks+1][t][p] = [X.q1,X.q3,Y.q1,Y.q3] (B-word p+2)
        #pragma unroll
        for (int p = 0; p < 2; p++) {
          asm volatile("v_permlane32_swap_b32 %0, %1"
                       : "+v"(Pp[2 * ks][t][p]), "+v"(Pp[2 * ks + 1][t][p]));
          asm volatile("v_permlane16_swap_b32 %0, %1"
                       : "+v"(Pp[2 * ks][t][p]), "+v"(Pp[2 * ks + 1][t][p]));
        }
        union { bf16x8 v; unsigned int u[4]; } bh;
        bh.u[0] = Pp[2 * ks][t][0];
        bh.u[1] = Pp[2 * ks][t][1];
        bh.u[2] = Pp[2 * ks + 1][t][0];
        bh.u[3] = Pp[2 * ks + 1][t][1];
        #pragma unroll
        for (int td = 0; td < 8; td++) {
          bf16x8 a2 = *(const bf16x8*)(
              w2sw + ((((td >> 2) * 16 + ks * 4 + (td & 3)) * 64) + lane) * 8);
          acc2[td] = MFMA32(a2, bh.v, acc2[td]);
        }
      }
      if (tm == 0) {
        #pragma unroll
        for (int td = 0; td < 8; td++) pooled[td] = acc2[td] + mf[0];
      } else {
        #pragma unroll
        for (int td = 0; td < 8; td++)
          pooled[td] = vmax4(pooled[td], acc2[td] + mf[tm]);
      }
    }
  }

  // ---- final pool over li: 16-lane shuffle reduce (xor 1,2,4,8) ----
  #pragma unroll
  for (int td = 0; td < 8; td++) {
    #pragma unroll
    for (int sm = 1; sm < 16; sm <<= 1)
      pooled[td] = vmax4(pooled[td], shfl_xor4(pooled[td], sm));
  }

  // li==0 lanes (q=0..3) hold the pool; add b2, zero-fix, 16B stores
  if (li == 0) {
    float* op = out + poly * 128 + q * 4;
    #pragma unroll
    for (int td = 0; td < 8; td++) {
      f32x4 v = pooled[td] + *(const f32x4*)(b2g + td * 16 + q * 4);
      #pragma unroll
      for (int j = 0; j < 4; j++) if (v[j] < -1e8f) v[j] = 0.f;
      *(f32x4*)(op + td * 16) = v;
    }
  }
}

extern "C" void kernel_launch(void* const* d_in, const int* in_sizes, int n_in,
                              void* d_out, int out_size, void* d_ws, size_t ws_size,
                              hipStream_t stream) {
  const float* X    = (const float*)d_in[0];
  const void*  mask = d_in[1];
  const float* W1   = (const float*)d_in[2];
  const float* b1   = (const float*)d_in[3];
  const float* W2   = (const float*)d_in[4];
  const float* b2   = (const float*)d_in[5];
  float* out = (float*)d_out;

  unsigned short* w1sw = (unsigned short*)d_ws;
  unsigned short* w2sw = (unsigned short*)((char*)d_ws + 8192);
  int* flag            = (int*)((char*)d_ws + 40960);

  prep1<<<11, 256, 0, stream>>>(W1, W2, mask, w1sw, w2sw, flag);
  poly_main_k<<<4096, 256, 0, stream>>>(X, mask, b1, b2, w1sw, w2sw, flag, out);
}

// Round 4
// 176.034 us; speedup vs baseline: 1.5337x; 1.5337x over previous
//
#include <hip/hip_runtime.h>

// PolylineEncoder: h = relu(X@W1+b1); feat = h@W2+b2; masked max over N=64 points.
// B=32 P=512 N=64 C=9 H=128.
// R11: independent-wave design, no barriers, no Hb LDS, hoisted weights.
//   - Wave pair (2 waves) covers 2 polylines: EACH wave computes layer-1 fully
//     (all 128 h; +20% MFMA, duplicated across the pair) and layer-2 for its
//     OWN d-half (64 d) -> w2 hoist is 16 frags (64 regs), amortized over 2
//     polylines => weight L2 traffic 393MB (~11us), vs R9's 2.2GB (~64us wall).
//   - Permlane32/16 in-register h->k transpose (R10-verified algebra).
//   - b1 folded into w1sw k=9 row; bx sets k9=1.0 (C=9 < 32 k-slots).
//   - One m-tile (16 pts) end-to-end at a time: Pp live set = 16 regs.
//   - launch_bounds(256,3): ~170-reg budget fits the 166-reg audit (R10 lesson:
//     the 128 budget spilled 246B/thread).
// R7/R9 lesson: 75us wall = max(L2 weight traffic, barrier'd-wave latency);
// this design removes both.

using bf16x8 = __attribute__((ext_vector_type(8))) short;
using f32x4  = __attribute__((ext_vector_type(4))) float;

#define MFMA32(A,B,C) __builtin_amdgcn_mfma_f32_16x16x32_bf16((A),(B),(C),0,0,0)

__device__ __forceinline__ f32x4 vmax4(f32x4 a, f32x4 b) {
  return __builtin_elementwise_max(a, b);
}

__device__ __forceinline__ unsigned short f2bf(float f) {
  union { float f; unsigned int u; } v; v.f = f;
  unsigned int r = v.u + 0x7fffu + ((v.u >> 16) & 1u);  // RNE
  return (unsigned short)(r >> 16);
}

// hardware packed f32->bf16 (RNE), low=a high=b: 1 VALU per 2 elems
__device__ __forceinline__ unsigned int pk2(float a, float b) {
  unsigned int r;
  asm("v_cvt_pk_bf16_f32 %0, %1, %2" : "=v"(r) : "v"(a), "v"(b));
  return r;
}

__device__ __forceinline__ f32x4 shfl_xor4(f32x4 v, int m) {
  f32x4 r;
  r[0] = __shfl_xor(v[0], m);
  r[1] = __shfl_xor(v[1], m);
  r[2] = __shfl_xor(v[2], m);
  r[3] = __shfl_xor(v[3], m);
  return r;
}

// ---------------- prep1: mask sniff + frag-swizzled weights ----------------
// ws: w1sw @0 (8KB) | w2sw @8192 (32KB) | flag @40960
// w1sw k-row 9 carries b1 (bx supplies k9 = 1.0).
__global__ void prep1(const float* __restrict__ W1, const float* __restrict__ b1,
                      const float* __restrict__ W2, const void* __restrict__ mask,
                      unsigned short* __restrict__ w1sw, unsigned short* __restrict__ w2sw,
                      int* __restrict__ flag) {
  int b = blockIdx.x, t = threadIdx.x;
  if (b == 0) {                      // mask storage sniff over 4096 bytes
    __shared__ int cnt;
    if (t == 0) cnt = 0;
    __syncthreads();
    const unsigned char* mb = (const unsigned char*)mask;
    int local = 0;
    for (int i = t * 16; i < t * 16 + 16; i++) local += (mb[i] != 0) ? 1 : 0;
    atomicAdd(&cnt, local);
    __syncthreads();
    if (t == 0) *flag = (cnt > 2800) ? 1 : 0;   // 1 = byte-wise mask, else int32-wise
  } else if (b <= 2) {
    // w1 A-frags (16x16x32): entry e = th*64 + lane; h=(e>>6)*16+(lane&15)
    int e = (b - 1) * 256 + t;       // 512 entries x 8 halves = 8KB
    int lane = e & 63, grp = e >> 6;
    int li = lane & 15, q = lane >> 4;
    int h = grp * 16 + li;
    int c0 = q * 8;
    #pragma unroll
    for (int j = 0; j < 8; j++) {
      int c = c0 + j;
      float v = (c < 9) ? W1[c * 128 + h] : ((c == 9) ? b1[h] : 0.f);
      w1sw[e * 8 + j] = f2bf(v);
    }
  } else {
    // w2 A-frags (16x16x32): entry e = (wr*16+ks*4+td)*64 + lane; 8 halves each
    int e = (b - 3) * 256 + t;       // 2048 entries x 8 halves = 32KB
    if (e < 2048) {
      int lane = e & 63, grp = e >> 6;
      int wr = grp >> 4, sub = grp & 15;
      int ks = sub >> 2, td = sub & 3;
      int li = lane & 15, q = lane >> 4;
      int d = wr * 64 + td * 16 + li;
      int h0 = ks * 32 + q * 8;
      #pragma unroll
      for (int j = 0; j < 8; j++)
        w2sw[e * 8 + j] = f2bf(W2[(h0 + j) * 128 + d]);
    }
  }
}

// ---------------- main ----------------
// 4 waves/block = 2 pairs; pair p handles polylines {blk*4+2p, blk*4+2p+1}.
// Wave w: pair = w>>1, dhalf = w&1.  No __syncthreads anywhere.
// LDS: 4 x 4608B per-wave X staging slots.
__global__ __launch_bounds__(256, 3) void poly_main_k(
    const float* __restrict__ X, const void* __restrict__ mask,
    const float* __restrict__ b2g,
    const unsigned short* __restrict__ w1sw, const unsigned short* __restrict__ w2sw,
    const int* __restrict__ flagp, float* __restrict__ out)
{
  __shared__ __align__(16) unsigned char smem[18432];

  const int tid  = threadIdx.x;
  const int lane = tid & 63;
  const int w    = tid >> 6;
  const int li   = lane & 15, q = lane >> 4;
  const int pair = w >> 1, dhalf = w & 1;
  const long long poly0 = (long long)blockIdx.x * 4 + pair * 2;

  // ---- stage this pair's 2 polylines (4608B) into own wave slot ----
  {
    const char* xg = (const char*)X + poly0 * 2304;
    char* xl = (char*)smem + w * 4608;
    #pragma unroll
    for (int k = 0; k < 4; k++)
      __builtin_amdgcn_global_load_lds(
          (const __attribute__((address_space(1))) unsigned int*)(xg + k * 1024 + lane * 16),
          (__attribute__((address_space(3))) unsigned int*)(xl + k * 1024), 16, 0, 0);
    if (lane < 32)
      __builtin_amdgcn_global_load_lds(
          (const __attribute__((address_space(1))) unsigned int*)(xg + 4096 + lane * 16),
          (__attribute__((address_space(3))) unsigned int*)(xl + 4096), 16, 0, 0);
  }

  const int flag = *flagp;

  // ---- hoist weight frags: w1 8x4=32 regs, w2 (own d-half) 16x4=64 regs ----
  bf16x8 w1f[8];
  #pragma unroll
  for (int th = 0; th < 8; th++)
    w1f[th] = *(const bf16x8*)(w1sw + (th * 64 + lane) * 8);

  bf16x8 w2f[4][4];
  #pragma unroll
  for (int ks = 0; ks < 4; ks++)
    #pragma unroll
    for (int td = 0; td < 4; td++)
      w2f[ks][td] = *(const bf16x8*)(w2sw + ((dhalf * 16 + ks * 4 + td) * 64 + lane) * 8);

  asm volatile("s_waitcnt vmcnt(0)" ::: "memory");  // staging + hoists complete

  const float* Xw = (const float*)(smem + w * 4608);

  #pragma unroll
  for (int pl = 0; pl < 2; pl++) {
    const long long poly = poly0 + pl;

    // ---- mask: 4 direct loads per lane ----
    float mf[4];
    {
      long long mb = poly * 64 + li;
      if (flag) {
        const unsigned char* mp = (const unsigned char*)mask;
        #pragma unroll
        for (int tm = 0; tm < 4; tm++) mf[tm] = mp[mb + tm * 16] ? 0.f : -4e9f;
      } else {
        const int* mp = (const int*)mask;
        #pragma unroll
        for (int tm = 0; tm < 4; tm++) mf[tm] = mp[mb + tm * 16] ? 0.f : -4e9f;
      }
    }

    f32x4 pooled[4];
    #pragma unroll
    for (int mt = 0; mt < 4; mt++) {
      // ---- layer-1 B-frag for this m-tile (k9 = 1.0 -> bias row) ----
      const float* xr = Xw + pl * 576 + (mt * 16 + li) * 9;
      union { bf16x8 v; unsigned int u[4]; } uu;
      uu.u[0] = uu.u[1] = uu.u[2] = uu.u[3] = 0u;
      if (q == 0) {
        uu.u[0] = pk2(xr[0], xr[1]); uu.u[1] = pk2(xr[2], xr[3]);
        uu.u[2] = pk2(xr[4], xr[5]); uu.u[3] = pk2(xr[6], xr[7]);
      } else if (q == 1) {
        uu.u[0] = pk2(xr[8], 1.0f);
      }
      const bf16x8 bx = uu.v;

      // ---- layer 1: all 128 h for these 16 points -> packed bf16 ----
      unsigned int Pp[8][2];
      #pragma unroll
      for (int th = 0; th < 8; th++) {
        f32x4 a = f32x4{0.f, 0.f, 0.f, 0.f};
        a = MFMA32(w1f[th], bx, a);
        f32x4 v = vmax4(a, f32x4{0.f, 0.f, 0.f, 0.f});
        Pp[th][0] = pk2(v[0], v[1]);
        Pp[th][1] = pk2(v[2], v[3]);
      }

      // ---- in-register h->k transpose (R10-verified) ----
      #pragma unroll
      for (int ks = 0; ks < 4; ks++)
        #pragma unroll
        for (int p = 0; p < 2; p++) {
          asm volatile("v_permlane32_swap_b32 %0, %1"
                       : "+v"(Pp[2 * ks][p]), "+v"(Pp[2 * ks + 1][p]));
          asm volatile("v_permlane16_swap_b32 %0, %1"
                       : "+v"(Pp[2 * ks][p]), "+v"(Pp[2 * ks + 1][p]));
        }

      // ---- layer 2 (own d-half) ----
      f32x4 acc2[4];
      #pragma unroll
      for (int td = 0; td < 4; td++) acc2[td] = f32x4{0.f, 0.f, 0.f, 0.f};
      #pragma unroll
      for (int ks = 0; ks < 4; ks++) {
        union { bf16x8 v; unsigned int u[4]; } bh;
        bh.u[0] = Pp[2 * ks][0];
        bh.u[1] = Pp[2 * ks][1];
        bh.u[2] = Pp[2 * ks + 1][0];
        bh.u[3] = Pp[2 * ks + 1][1];
        #pragma unroll
        for (int td = 0; td < 4; td++)
          acc2[td] = MFMA32(w2f[ks][td], bh.v, acc2[td]);
      }

      // ---- incremental pool over m-tiles ----
      if (mt == 0) {
        #pragma unroll
        for (int td = 0; td < 4; td++) pooled[td] = acc2[td] + mf[0];
      } else {
        #pragma unroll
        for (int td = 0; td < 4; td++)
          pooled[td] = vmax4(pooled[td], acc2[td] + mf[mt]);
      }
    }

    // ---- final pool over li: 16-lane shuffle reduce ----
    #pragma unroll
    for (int td = 0; td < 4; td++) {
      #pragma unroll
      for (int sm = 1; sm < 16; sm <<= 1)
        pooled[td] = vmax4(pooled[td], shfl_xor4(pooled[td], sm));
    }

    // li==0 lanes (q=0..3) hold the pool; add b2, zero-fix, 16B stores
    if (li == 0) {
      float* op = out + poly * 128 + dhalf * 64 + q * 4;
      #pragma unroll
      for (int td = 0; td < 4; td++) {
        f32x4 v = pooled[td] + *(const f32x4*)(b2g + dhalf * 64 + td * 16 + q * 4);
        #pragma unroll
        for (int j = 0; j < 4; j++) if (v[j] < -1e8f) v[j] = 0.f;
        *(f32x4*)(op + td * 16) = v;
      }
    }
  }
}

extern "C" void kernel_launch(void* const* d_in, const int* in_sizes, int n_in,
                              void* d_out, int out_size, void* d_ws, size_t ws_size,
                              hipStream_t stream) {
  const float* X    = (const float*)d_in[0];
  const void*  mask = d_in[1];
  const float* W1   = (const float*)d_in[2];
  const float* b1   = (const float*)d_in[3];
  const float* W2   = (const float*)d_in[4];
  const float* b2   = (const float*)d_in[5];
  float* out = (float*)d_out;

  unsigned short* w1sw = (unsigned short*)d_ws;
  unsigned short* w2sw = (unsigned short*)((char*)d_ws + 8192);
  int* flag            = (int*)((char*)d_ws + 40960);

  prep1<<<11, 256, 0, stream>>>(W1, b1, W2, mask, w1sw, w2sw, flag);
  poly_main_k<<<4096, 256, 0, stream>>>(X, mask, b2, w1sw, w2sw, flag, out);
}

// Round 5
// 160.822 us; speedup vs baseline: 1.6787x; 1.0946x over previous
//
#include <hip/hip_runtime.h>

// PolylineEncoder: h = relu(X@W1+b1); feat = h@W2+b2; masked max over N=64 points.
// B=32 P=512 N=64 C=9 H=128.
// R12: wave-per-polyline permlane design (R10/R11 algebra, both PASSED) inside a
// no-spill register envelope.
//   Allocator model from R7-R11 VGPR_Counts: unified budget splits EVENLY into
//   arch VGPR + AGPR (64/64 @ (256,4); 84/84 @ (256,3)).  Spill = arch demand
//   over the half-cap (R10: ~100>64; R11: ~95>84 + 96-reg hoist > AGPR half).
//   Fix: __launch_bounds__(256,2) -> 128 arch worst-case vs ~115 demand.
//   - 1 wave = 2 polylines (serial), full 128-h layer1 + full 128-d layer2.
//   - permlane32/16 in-register h->k transpose; NO Hb LDS, NO barriers,
//     no bank conflicts; waves fully independent.
//   - NO weight hoist (R11 lesson); frags re-read from L1 (40KB working set).
//   - b1 folded into w1sw k=9 row (R11-proven); k9=1.0 in bx.
//   - tc-chunked layer 2: acc[2 td][2 mt], frag loaded once per (tc,ks,j),
//     reused across both m-tiles.
//   - X staged via global_load_lds (R10/R11-proven), per-wave vmcnt wait.

using bf16x8 = __attribute__((ext_vector_type(8))) short;
using f32x4  = __attribute__((ext_vector_type(4))) float;

#define MFMA32(A,B,C) __builtin_amdgcn_mfma_f32_16x16x32_bf16((A),(B),(C),0,0,0)

__device__ __forceinline__ f32x4 vmax4(f32x4 a, f32x4 b) {
  return __builtin_elementwise_max(a, b);
}

__device__ __forceinline__ unsigned short f2bf(float f) {
  union { float f; unsigned int u; } v; v.f = f;
  unsigned int r = v.u + 0x7fffu + ((v.u >> 16) & 1u);  // RNE
  return (unsigned short)(r >> 16);
}

// hardware packed f32->bf16 (RNE), low=a high=b: 1 VALU per 2 elems
__device__ __forceinline__ unsigned int pk2(float a, float b) {
  unsigned int r;
  asm("v_cvt_pk_bf16_f32 %0, %1, %2" : "=v"(r) : "v"(a), "v"(b));
  return r;
}

__device__ __forceinline__ f32x4 shfl_xor4(f32x4 v, int m) {
  f32x4 r;
  r[0] = __shfl_xor(v[0], m);
  r[1] = __shfl_xor(v[1], m);
  r[2] = __shfl_xor(v[2], m);
  r[3] = __shfl_xor(v[3], m);
  return r;
}

// ---------------- prep1: mask sniff + frag-swizzled weights ----------------
// ws: w1sw @0 (8KB) | w2sw @8192 (32KB) | flag @40960
// w1sw k-row 9 carries b1 (bx supplies k9 = 1.0).
__global__ void prep1(const float* __restrict__ W1, const float* __restrict__ b1,
                      const float* __restrict__ W2, const void* __restrict__ mask,
                      unsigned short* __restrict__ w1sw, unsigned short* __restrict__ w2sw,
                      int* __restrict__ flag) {
  int b = blockIdx.x, t = threadIdx.x;
  if (b == 0) {                      // mask storage sniff over 4096 bytes
    __shared__ int cnt;
    if (t == 0) cnt = 0;
    __syncthreads();
    const unsigned char* mb = (const unsigned char*)mask;
    int local = 0;
    for (int i = t * 16; i < t * 16 + 16; i++) local += (mb[i] != 0) ? 1 : 0;
    atomicAdd(&cnt, local);
    __syncthreads();
    if (t == 0) *flag = (cnt > 2800) ? 1 : 0;   // 1 = byte-wise mask, else int32-wise
  } else if (b <= 2) {
    // w1 A-frags (16x16x32): entry e = th*64 + lane; h=(e>>6)*16+(lane&15)
    int e = (b - 1) * 256 + t;       // 512 entries x 8 halves = 8KB
    int lane = e & 63, grp = e >> 6;
    int li = lane & 15, q = lane >> 4;
    int h = grp * 16 + li;
    int c0 = q * 8;
    #pragma unroll
    for (int j = 0; j < 8; j++) {
      int c = c0 + j;
      float v = (c < 9) ? W1[c * 128 + h] : ((c == 9) ? b1[h] : 0.f);
      w1sw[e * 8 + j] = f2bf(v);
    }
  } else {
    // w2 A-frags (16x16x32): entry e = (wr*16+ks*4+td)*64 + lane; 8 halves each
    int e = (b - 3) * 256 + t;       // 2048 entries x 8 halves = 32KB
    if (e < 2048) {
      int lane = e & 63, grp = e >> 6;
      int wr = grp >> 4, sub = grp & 15;
      int ks = sub >> 2, td = sub & 3;
      int li = lane & 15, q = lane >> 4;
      int d = wr * 64 + td * 16 + li;
      int h0 = ks * 32 + q * 8;
      #pragma unroll
      for (int j = 0; j < 8; j++)
        w2sw[e * 8 + j] = f2bf(W2[(h0 + j) * 128 + d]);
    }
  }
}

// ---------------- main ----------------
// 4 waves/block, each wave owns 2 polylines end-to-end.  Grid 2048.
// LDS: 4 x 4608B per-wave X slots.  No __syncthreads anywhere.
__global__ __launch_bounds__(256, 2) void poly_main_k(
    const float* __restrict__ X, const void* __restrict__ mask,
    const float* __restrict__ b2g,
    const unsigned short* __restrict__ w1sw, const unsigned short* __restrict__ w2sw,
    const int* __restrict__ flagp, float* __restrict__ out)
{
  __shared__ __align__(16) unsigned char smem[18432];

  const int tid  = threadIdx.x;
  const int lane = tid & 63;
  const int w    = tid >> 6;
  const int li   = lane & 15, q = lane >> 4;
  const long long poly0 = (long long)blockIdx.x * 8 + w * 2;

  // ---- stage this wave's 2 polylines (4608B) into own slot ----
  {
    const char* xg = (const char*)X + poly0 * 2304;
    char* xl = (char*)smem + w * 4608;
    #pragma unroll
    for (int k = 0; k < 4; k++)
      __builtin_amdgcn_global_load_lds(
          (const __attribute__((address_space(1))) unsigned int*)(xg + k * 1024 + lane * 16),
          (__attribute__((address_space(3))) unsigned int*)(xl + k * 1024), 16, 0, 0);
    if (lane < 32)
      __builtin_amdgcn_global_load_lds(
          (const __attribute__((address_space(1))) unsigned int*)(xg + 4096 + lane * 16),
          (__attribute__((address_space(3))) unsigned int*)(xl + 4096), 16, 0, 0);
  }

  const int flag = *flagp;

  asm volatile("s_waitcnt vmcnt(0)" ::: "memory");  // staging complete

  #pragma unroll
  for (int pl = 0; pl < 2; pl++) {
    const long long poly = poly0 + pl;
    const float* Xp = (const float*)(smem + w * 4608 + pl * 2304);

    // ---- mask: 4 direct loads per lane ----
    float mf[4];
    {
      long long mb = poly * 64 + li;
      if (flag) {
        const unsigned char* mp = (const unsigned char*)mask;
        #pragma unroll
        for (int tm = 0; tm < 4; tm++) mf[tm] = mp[mb + tm * 16] ? 0.f : -4e9f;
      } else {
        const int* mp = (const int*)mask;
        #pragma unroll
        for (int tm = 0; tm < 4; tm++) mf[tm] = mp[mb + tm * 16] ? 0.f : -4e9f;
      }
    }

    f32x4 pooled[8];
    #pragma unroll
    for (int hf = 0; hf < 2; hf++) {
      // ---- layer-1 B-frags for this half's 2 m-tiles (k9 = 1.0 bias row) ----
      bf16x8 bx2[2];
      #pragma unroll
      for (int t = 0; t < 2; t++) {
        const float* xr = Xp + ((hf * 2 + t) * 16 + li) * 9;
        union { bf16x8 v; unsigned int u[4]; } uu;
        uu.u[0] = uu.u[1] = uu.u[2] = uu.u[3] = 0u;
        if (q == 0) {
          uu.u[0] = pk2(xr[0], xr[1]); uu.u[1] = pk2(xr[2], xr[3]);
          uu.u[2] = pk2(xr[4], xr[5]); uu.u[3] = pk2(xr[6], xr[7]);
        } else if (q == 1) {
          uu.u[0] = pk2(xr[8], 1.0f);
        }
        bx2[t] = uu.v;
      }

      // ---- layer 1: all 128 h for these 32 points -> packed bf16 ----
      unsigned int Pp[8][2][2];
      #pragma unroll
      for (int th = 0; th < 8; th++) {
        bf16x8 a1 = *(const bf16x8*)(w1sw + (th * 64 + lane) * 8);
        f32x4 acc0 = f32x4{0.f, 0.f, 0.f, 0.f};
        f32x4 acc1 = f32x4{0.f, 0.f, 0.f, 0.f};
        acc0 = MFMA32(a1, bx2[0], acc0);
        acc1 = MFMA32(a1, bx2[1], acc1);
        f32x4 v0 = vmax4(acc0, f32x4{0.f, 0.f, 0.f, 0.f});
        f32x4 v1 = vmax4(acc1, f32x4{0.f, 0.f, 0.f, 0.f});
        Pp[th][0][0] = pk2(v0[0], v0[1]); Pp[th][0][1] = pk2(v0[2], v0[3]);
        Pp[th][1][0] = pk2(v1[0], v1[1]); Pp[th][1][1] = pk2(v1[2], v1[3]);
      }

      // ---- in-register h->k transpose (R10/R11-verified) ----
      #pragma unroll
      for (int t = 0; t < 2; t++)
        #pragma unroll
        for (int ks = 0; ks < 4; ks++)
          #pragma unroll
          for (int p = 0; p < 2; p++) {
            asm volatile("v_permlane32_swap_b32 %0, %1"
                         : "+v"(Pp[2 * ks][t][p]), "+v"(Pp[2 * ks + 1][t][p]));
            asm volatile("v_permlane16_swap_b32 %0, %1"
                         : "+v"(Pp[2 * ks][t][p]), "+v"(Pp[2 * ks + 1][t][p]));
          }

      // ---- layer 2, tc-chunked (td pairs), frag reused across both m-tiles ----
      #pragma unroll
      for (int tc = 0; tc < 4; tc++) {
        f32x4 acc[2][2];
        #pragma unroll
        for (int j = 0; j < 2; j++) {
          acc[j][0] = f32x4{0.f, 0.f, 0.f, 0.f};
          acc[j][1] = f32x4{0.f, 0.f, 0.f, 0.f};
        }
        #pragma unroll
        for (int ks = 0; ks < 4; ks++) {
          union { bf16x8 v; unsigned int u[4]; } bh0, bh1;
          bh0.u[0] = Pp[2 * ks][0][0]; bh0.u[1] = Pp[2 * ks][0][1];
          bh0.u[2] = Pp[2 * ks + 1][0][0]; bh0.u[3] = Pp[2 * ks + 1][0][1];
          bh1.u[0] = Pp[2 * ks][1][0]; bh1.u[1] = Pp[2 * ks][1][1];
          bh1.u[2] = Pp[2 * ks + 1][1][0]; bh1.u[3] = Pp[2 * ks + 1][1][1];
          #pragma unroll
          for (int j = 0; j < 2; j++) {
            const int td = tc * 2 + j;
            bf16x8 a2 = *(const bf16x8*)(
                w2sw + ((((td >> 2) * 16 + ks * 4 + (td & 3)) * 64) + lane) * 8);
            acc[j][0] = MFMA32(a2, bh0.v, acc[j][0]);
            acc[j][1] = MFMA32(a2, bh1.v, acc[j][1]);
          }
        }
        // pool this td-pair over the 2 m-tiles (+ mask), merge across halves
        #pragma unroll
        for (int j = 0; j < 2; j++) {
          const int td = tc * 2 + j;
          f32x4 v = vmax4(acc[j][0] + mf[hf * 2 + 0], acc[j][1] + mf[hf * 2 + 1]);
          pooled[td] = (hf == 0) ? v : vmax4(pooled[td], v);
        }
      }
    }

    // ---- final pool over li: 16-lane shuffle reduce (xor 1,2,4,8) ----
    #pragma unroll
    for (int td = 0; td < 8; td++) {
      #pragma unroll
      for (int sm = 1; sm < 16; sm <<= 1)
        pooled[td] = vmax4(pooled[td], shfl_xor4(pooled[td], sm));
    }

    // li==0 lanes (q=0..3) hold the pool; add b2, zero-fix, 16B stores
    if (li == 0) {
      float* op = out + poly * 128 + q * 4;
      #pragma unroll
      for (int td = 0; td < 8; td++) {
        f32x4 v = pooled[td] + *(const f32x4*)(b2g + td * 16 + q * 4);
        #pragma unroll
        for (int j = 0; j < 4; j++) if (v[j] < -1e8f) v[j] = 0.f;
        *(f32x4*)(op + td * 16) = v;
      }
    }
  }
}

extern "C" void kernel_launch(void* const* d_in, const int* in_sizes, int n_in,
                              void* d_out, int out_size, void* d_ws, size_t ws_size,
                              hipStream_t stream) {
  const float* X    = (const float*)d_in[0];
  const void*  mask = d_in[1];
  const float* W1   = (const float*)d_in[2];
  const float* b1   = (const float*)d_in[3];
  const float* W2   = (const float*)d_in[4];
  const float* b2   = (const float*)d_in[5];
  float* out = (float*)d_out;

  unsigned short* w1sw = (unsigned short*)d_ws;
  unsigned short* w2sw = (unsigned short*)((char*)d_ws + 8192);
  int* flag            = (int*)((char*)d_ws + 40960);

  prep1<<<11, 256, 0, stream>>>(W1, b1, W2, mask, w1sw, w2sw, flag);
  poly_main_k<<<2048, 256, 0, stream>>>(X, mask, b2, w1sw, w2sw, flag, out);
}

// Round 6
// 144.563 us; speedup vs baseline: 1.8675x; 1.1125x over previous
//
#include <hip/hip_runtime.h>

// PolylineEncoder: h = relu(X@W1+b1); feat = h@W2+b2; masked max over N=64 points.
// B=32 P=512 N=64 C=9 H=128.
// R13 = R12 permlane body (PASSED, spill-free, VGPR=120) + LDS-resident weights.
//   R12 lesson: no spill but 117us -> per-wave weight frag re-reads = 1.3GB of
//   L1-miss/L2 traffic (38us floor) + unhidden L2 latency at 2-4 waves/SIMD.
//   Fix: block stages all 40KB of frag-swizzled weights into LDS ONCE
//   (41MB total global traffic, L2-resident), frags served by ds_read_b128
//   (~120cyc, LDS pipe ~720cyc/polyline vs MFMA ~770cyc/polyline: balanced).
//   - 512-thr blocks (8 waves), wave owns 2 polylines, grid 1024.
//   - LDS: weights 40960B + 8x4608B X slots = 76KB -> 2 blocks/CU, 16 waves/CU
//     (4/SIMD, 2x R12's occupancy).
//   - ONE __syncthreads (after weight+X staging); waves independent after.
//   - launch_bounds(512,4): 128-reg cap vs 120 measured demand (R12) -> fits.
//   - permlane32/16 h->k transpose, b1 folded in w1sw k=9 row, k9=1.0 in bx,
//     16-lane shuffle final pool, zero Hb, zero bank-conflict frag layout.

using bf16x8 = __attribute__((ext_vector_type(8))) short;
using f32x4  = __attribute__((ext_vector_type(4))) float;

#define MFMA32(A,B,C) __builtin_amdgcn_mfma_f32_16x16x32_bf16((A),(B),(C),0,0,0)

__device__ __forceinline__ f32x4 vmax4(f32x4 a, f32x4 b) {
  return __builtin_elementwise_max(a, b);
}

__device__ __forceinline__ unsigned short f2bf(float f) {
  union { float f; unsigned int u; } v; v.f = f;
  unsigned int r = v.u + 0x7fffu + ((v.u >> 16) & 1u);  // RNE
  return (unsigned short)(r >> 16);
}

// hardware packed f32->bf16 (RNE), low=a high=b: 1 VALU per 2 elems
__device__ __forceinline__ unsigned int pk2(float a, float b) {
  unsigned int r;
  asm("v_cvt_pk_bf16_f32 %0, %1, %2" : "=v"(r) : "v"(a), "v"(b));
  return r;
}

__device__ __forceinline__ f32x4 shfl_xor4(f32x4 v, int m) {
  f32x4 r;
  r[0] = __shfl_xor(v[0], m);
  r[1] = __shfl_xor(v[1], m);
  r[2] = __shfl_xor(v[2], m);
  r[3] = __shfl_xor(v[3], m);
  return r;
}

// ---------------- prep1: mask sniff + frag-swizzled weights ----------------
// ws: w1sw @0 (8KB) | w2sw @8192 (32KB) | flag @40960
// w1sw k-row 9 carries b1 (bx supplies k9 = 1.0).
__global__ void prep1(const float* __restrict__ W1, const float* __restrict__ b1,
                      const float* __restrict__ W2, const void* __restrict__ mask,
                      unsigned short* __restrict__ w1sw, unsigned short* __restrict__ w2sw,
                      int* __restrict__ flag) {
  int b = blockIdx.x, t = threadIdx.x;
  if (b == 0) {                      // mask storage sniff over 4096 bytes
    __shared__ int cnt;
    if (t == 0) cnt = 0;
    __syncthreads();
    const unsigned char* mb = (const unsigned char*)mask;
    int local = 0;
    for (int i = t * 16; i < t * 16 + 16; i++) local += (mb[i] != 0) ? 1 : 0;
    atomicAdd(&cnt, local);
    __syncthreads();
    if (t == 0) *flag = (cnt > 2800) ? 1 : 0;   // 1 = byte-wise mask, else int32-wise
  } else if (b <= 2) {
    // w1 A-frags (16x16x32): entry e = th*64 + lane; h=(e>>6)*16+(lane&15)
    int e = (b - 1) * 256 + t;       // 512 entries x 8 halves = 8KB
    int lane = e & 63, grp = e >> 6;
    int li = lane & 15, q = lane >> 4;
    int h = grp * 16 + li;
    int c0 = q * 8;
    #pragma unroll
    for (int j = 0; j < 8; j++) {
      int c = c0 + j;
      float v = (c < 9) ? W1[c * 128 + h] : ((c == 9) ? b1[h] : 0.f);
      w1sw[e * 8 + j] = f2bf(v);
    }
  } else {
    // w2 A-frags (16x16x32): entry e = (wr*16+ks*4+td)*64 + lane; 8 halves each
    int e = (b - 3) * 256 + t;       // 2048 entries x 8 halves = 32KB
    if (e < 2048) {
      int lane = e & 63, grp = e >> 6;
      int wr = grp >> 4, sub = grp & 15;
      int ks = sub >> 2, td = sub & 3;
      int li = lane & 15, q = lane >> 4;
      int d = wr * 64 + td * 16 + li;
      int h0 = ks * 32 + q * 8;
      #pragma unroll
      for (int j = 0; j < 8; j++)
        w2sw[e * 8 + j] = f2bf(W2[(h0 + j) * 128 + d]);
    }
  }
}

// ---------------- main ----------------
// 8 waves/block (512 thr), each wave owns 2 polylines.  Grid 1024.
// LDS: weights [0,40960) | X slots [40960, 40960+8*4608).
// One __syncthreads (weights ready); waves independent afterward.
__global__ __launch_bounds__(512, 4) void poly_main_k(
    const float* __restrict__ X, const void* __restrict__ mask,
    const float* __restrict__ b2g,
    const unsigned short* __restrict__ w1sw, const unsigned short* __restrict__ w2sw,
    const int* __restrict__ flagp, float* __restrict__ out)
{
  __shared__ __align__(16) unsigned char smem[77824];
  const unsigned short* Wl1 = (const unsigned short*)smem;            // 8KB
  const unsigned short* Wl2 = (const unsigned short*)(smem + 8192);   // 32KB

  const int tid  = threadIdx.x;
  const int lane = tid & 63;
  const int w    = tid >> 6;
  const int li   = lane & 15, q = lane >> 4;
  const long long poly0 = (long long)blockIdx.x * 16 + w * 2;

  // ---- stage weights (40960B = 2560 x 16B; 512 thr x 5) into LDS ----
  {
    const char* wg = (const char*)w1sw;       // w1sw and w2sw are contiguous in ws
    #pragma unroll
    for (int k = 0; k < 5; k++) {
      __builtin_amdgcn_global_load_lds(
          (const __attribute__((address_space(1))) unsigned int*)(wg + k * 8192 + tid * 16),
          (__attribute__((address_space(3))) unsigned int*)(smem + k * 8192 + w * 1024),
          16, 0, 0);
    }
  }
  // ---- stage this wave's 2 polylines (4608B) into own X slot ----
  {
    const char* xg = (const char*)X + poly0 * 2304;
    char* xl = (char*)smem + 40960 + w * 4608;
    #pragma unroll
    for (int k = 0; k < 4; k++)
      __builtin_amdgcn_global_load_lds(
          (const __attribute__((address_space(1))) unsigned int*)(xg + k * 1024 + lane * 16),
          (__attribute__((address_space(3))) unsigned int*)(xl + k * 1024), 16, 0, 0);
    if (lane < 32)
      __builtin_amdgcn_global_load_lds(
          (const __attribute__((address_space(1))) unsigned int*)(xg + 4096 + lane * 16),
          (__attribute__((address_space(3))) unsigned int*)(xl + 4096), 16, 0, 0);
  }

  const int flag = *flagp;

  __syncthreads();   // weights + X staged (vmcnt drained before barrier)

  #pragma unroll
  for (int pl = 0; pl < 2; pl++) {
    const long long poly = poly0 + pl;
    const float* Xp = (const float*)(smem + 40960 + w * 4608 + pl * 2304);

    // ---- mask: 4 direct loads per lane ----
    float mf[4];
    {
      long long mb = poly * 64 + li;
      if (flag) {
        const unsigned char* mp = (const unsigned char*)mask;
        #pragma unroll
        for (int tm = 0; tm < 4; tm++) mf[tm] = mp[mb + tm * 16] ? 0.f : -4e9f;
      } else {
        const int* mp = (const int*)mask;
        #pragma unroll
        for (int tm = 0; tm < 4; tm++) mf[tm] = mp[mb + tm * 16] ? 0.f : -4e9f;
      }
    }

    f32x4 pooled[8];
    #pragma unroll
    for (int hf = 0; hf < 2; hf++) {
      // ---- layer-1 B-frags for this half's 2 m-tiles (k9 = 1.0 bias row) ----
      bf16x8 bx2[2];
      #pragma unroll
      for (int t = 0; t < 2; t++) {
        const float* xr = Xp + ((hf * 2 + t) * 16 + li) * 9;
        union { bf16x8 v; unsigned int u[4]; } uu;
        uu.u[0] = uu.u[1] = uu.u[2] = uu.u[3] = 0u;
        if (q == 0) {
          uu.u[0] = pk2(xr[0], xr[1]); uu.u[1] = pk2(xr[2], xr[3]);
          uu.u[2] = pk2(xr[4], xr[5]); uu.u[3] = pk2(xr[6], xr[7]);
        } else if (q == 1) {
          uu.u[0] = pk2(xr[8], 1.0f);
        }
        bx2[t] = uu.v;
      }

      // ---- layer 1: all 128 h for these 32 points -> packed bf16 ----
      unsigned int Pp[8][2][2];
      #pragma unroll
      for (int th = 0; th < 8; th++) {
        bf16x8 a1 = *(const bf16x8*)(Wl1 + (th * 64 + lane) * 8);
        f32x4 acc0 = f32x4{0.f, 0.f, 0.f, 0.f};
        f32x4 acc1 = f32x4{0.f, 0.f, 0.f, 0.f};
        acc0 = MFMA32(a1, bx2[0], acc0);
        acc1 = MFMA32(a1, bx2[1], acc1);
        f32x4 v0 = vmax4(acc0, f32x4{0.f, 0.f, 0.f, 0.f});
        f32x4 v1 = vmax4(acc1, f32x4{0.f, 0.f, 0.f, 0.f});
        Pp[th][0][0] = pk2(v0[0], v0[1]); Pp[th][0][1] = pk2(v0[2], v0[3]);
        Pp[th][1][0] = pk2(v1[0], v1[1]); Pp[th][1][1] = pk2(v1[2], v1[3]);
      }

      // ---- in-register h->k transpose (R10/R11/R12-verified) ----
      #pragma unroll
      for (int t = 0; t < 2; t++)
        #pragma unroll
        for (int ks = 0; ks < 4; ks++)
          #pragma unroll
          for (int p = 0; p < 2; p++) {
            asm volatile("v_permlane32_swap_b32 %0, %1"
                         : "+v"(Pp[2 * ks][t][p]), "+v"(Pp[2 * ks + 1][t][p]));
            asm volatile("v_permlane16_swap_b32 %0, %1"
                         : "+v"(Pp[2 * ks][t][p]), "+v"(Pp[2 * ks + 1][t][p]));
          }

      // ---- layer 2, tc-chunked (td pairs), frag reused across both m-tiles ----
      #pragma unroll
      for (int tc = 0; tc < 4; tc++) {
        f32x4 acc[2][2];
        #pragma unroll
        for (int j = 0; j < 2; j++) {
          acc[j][0] = f32x4{0.f, 0.f, 0.f, 0.f};
          acc[j][1] = f32x4{0.f, 0.f, 0.f, 0.f};
        }
        #pragma unroll
        for (int ks = 0; ks < 4; ks++) {
          union { bf16x8 v; unsigned int u[4]; } bh0, bh1;
          bh0.u[0] = Pp[2 * ks][0][0]; bh0.u[1] = Pp[2 * ks][0][1];
          bh0.u[2] = Pp[2 * ks + 1][0][0]; bh0.u[3] = Pp[2 * ks + 1][0][1];
          bh1.u[0] = Pp[2 * ks][1][0]; bh1.u[1] = Pp[2 * ks][1][1];
          bh1.u[2] = Pp[2 * ks + 1][1][0]; bh1.u[3] = Pp[2 * ks + 1][1][1];
          #pragma unroll
          for (int j = 0; j < 2; j++) {
            const int td = tc * 2 + j;
            bf16x8 a2 = *(const bf16x8*)(
                Wl2 + ((((td >> 2) * 16 + ks * 4 + (td & 3)) * 64) + lane) * 8);
            acc[j][0] = MFMA32(a2, bh0.v, acc[j][0]);
            acc[j][1] = MFMA32(a2, bh1.v, acc[j][1]);
          }
        }
        // pool this td-pair over the 2 m-tiles (+ mask), merge across halves
        #pragma unroll
        for (int j = 0; j < 2; j++) {
          const int td = tc * 2 + j;
          f32x4 v = vmax4(acc[j][0] + mf[hf * 2 + 0], acc[j][1] + mf[hf * 2 + 1]);
          pooled[td] = (hf == 0) ? v : vmax4(pooled[td], v);
        }
      }
    }

    // ---- final pool over li: 16-lane shuffle reduce (xor 1,2,4,8) ----
    #pragma unroll
    for (int td = 0; td < 8; td++) {
      #pragma unroll
      for (int sm = 1; sm < 16; sm <<= 1)
        pooled[td] = vmax4(pooled[td], shfl_xor4(pooled[td], sm));
    }

    // li==0 lanes (q=0..3) hold the pool; add b2, zero-fix, 16B stores
    if (li == 0) {
      float* op = out + poly * 128 + q * 4;
      #pragma unroll
      for (int td = 0; td < 8; td++) {
        f32x4 v = pooled[td] + *(const f32x4*)(b2g + td * 16 + q * 4);
        #pragma unroll
        for (int j = 0; j < 4; j++) if (v[j] < -1e8f) v[j] = 0.f;
        *(f32x4*)(op + td * 16) = v;
      }
    }
  }
}

extern "C" void kernel_launch(void* const* d_in, const int* in_sizes, int n_in,
                              void* d_out, int out_size, void* d_ws, size_t ws_size,
                              hipStream_t stream) {
  const float* X    = (const float*)d_in[0];
  const void*  mask = d_in[1];
  const float* W1   = (const float*)d_in[2];
  const float* b1   = (const float*)d_in[3];
  const float* W2   = (const float*)d_in[4];
  const float* b2   = (const float*)d_in[5];
  float* out = (float*)d_out;

  unsigned short* w1sw = (unsigned short*)d_ws;
  unsigned short* w2sw = (unsigned short*)((char*)d_ws + 8192);
  int* flag            = (int*)((char*)d_ws + 40960);

  prep1<<<11, 256, 0, stream>>>(W1, b1, W2, mask, w1sw, w2sw, flag);
  poly_main_k<<<1024, 512, 0, stream>>>(X, mask, b2, w1sw, w2sw, flag, out);
}